// Round 1
// baseline (1108.042 us; speedup 1.0000x reference)
//
#include <hip/hip_runtime.h>
#include <hip/hip_fp16.h>

#define N 128
#define INF_ 1e9f

// float -> order-preserving u32 (ascending)
__device__ __forceinline__ unsigned f2ord(float f) {
    unsigned b = __float_as_uint(f);
    return b ^ ((unsigned)((int)b >> 31) | 0x80000000u);
}
__device__ __forceinline__ float ord2f(unsigned k) {
    unsigned b = k ^ ((unsigned)((int)(~k) >> 31) | 0x80000000u);
    return __uint_as_float(b);
}

// One batch per 64-lane wave. Lane l owns columns c0=l+1, c1=l+65 (1-based).
// Cost matrix staged in LDS as packed half2 (cols l, l+64) -> 32 KiB -> 4 blocks/CU.
__global__ void __launch_bounds__(64) lsa_solve_kernel(
        const float* __restrict__ x, const float* __restrict__ bias,
        float* __restrict__ out, int B) {
    __shared__ unsigned Cs[N][64];     // packed fp16 costs (= -x)
    __shared__ float u_lds[N + 1];
    __shared__ int   p_lds[N + 1];     // p[j] = row assigned to col j (1-based), 0 = free
    __shared__ int   way_lds[N + 1];
    __shared__ int   colOf[N + 1];     // row -> col (both 1-based)

    const int b = blockIdx.x;
    const int l = threadIdx.x;
    const int c0 = l + 1, c1 = l + 65;
    const float* xb = x + (size_t)b * (N * N);

    // ---- stage costs into LDS (coalesced, fp16-packed) ----
    #pragma unroll 4
    for (int r = 0; r < N; ++r) {
        float v0 = xb[r * N + l];
        float v1 = xb[r * N + l + 64];
        __half2 h = __floats2half2_rn(-v0, -v1);   // minimize -x
        Cs[r][l] = __builtin_bit_cast(unsigned, h);
    }
    u_lds[c0] = 0.f; u_lds[c1] = 0.f;
    p_lds[c0] = 0;   p_lds[c1] = 0;
    if (l == 0) { u_lds[0] = 0.f; p_lds[0] = 0; }
    __syncthreads();

    // per-lane column state
    float v0r = 0.f, v1r = 0.f;     // v[c0], v[c1]
    int prow0 = 0, prow1 = 0;       // p[c0], p[c1]

    #pragma unroll 1
    for (int i = 1; i <= N; ++i) {
        // ---- grow alternating tree (Dijkstra in absolute-distance form) ----
        float dist0 = INF_, dist1 = INF_;
        int way0 = 0, way1 = 0;
        bool used0 = false, used1 = false;
        float cumAt0 = 0.f, cumAt1 = 0.f;
        float cum = 0.f;
        int j0 = 0, i0 = i;
        int jfin = 0;

        #pragma unroll 1
        for (int it = 0; it <= N; ++it) {
            // mark j0 used, record cum at use time
            if (j0 == c0) { used0 = true; cumAt0 = cum; }
            if (j0 == c1) { used1 = true; cumAt1 = cum; }
            float u0 = u_lds[i0];
            unsigned pk = Cs[i0 - 1][l];
            __half2 h = __builtin_bit_cast(__half2, pk);
            float base = cum - u0;
            float cand0 = __low2float(h)  - v0r + base;  // abs reduced cost + cum
            float cand1 = __high2float(h) - v1r + base;
            if (!used0 && cand0 < dist0) { dist0 = cand0; way0 = j0; }
            if (!used1 && cand1 < dist1) { dist1 = cand1; way1 = j0; }

            // local argmin over my 2 columns (tie -> lower col, matches jnp.argmin)
            unsigned k0 = used0 ? 0xFFFFFFFFu : f2ord(dist0);
            unsigned k1 = used1 ? 0xFFFFFFFFu : f2ord(dist1);
            unsigned key; int cp;
            if (k1 < k0) { key = k1; cp = (c1 << 16) | prow1; }
            else         { key = k0; cp = (c0 << 16) | prow0; }
            // 64-lane butterfly min, carrying (col, p[col])
            #pragma unroll
            for (int off = 32; off > 0; off >>= 1) {
                unsigned ok = __shfl_xor(key, off);
                int ocp = __shfl_xor(cp, off);
                if (ok < key || (ok == key && ocp < cp)) { key = ok; cp = ocp; }
            }
            cum = ord2f(key);
            j0 = cp >> 16;
            i0 = cp & 0xFFFF;
            if (i0 == 0) { jfin = j0; break; }   // reached a free column
        }

        // ---- deferred potential updates: v[j]-=d, u[p[j]]+=d, d=cum_end-cum_at_use
        if (used0) { float dv = cum - cumAt0; v0r -= dv; u_lds[prow0] += dv; }
        if (used1) { float dv = cum - cumAt1; v1r -= dv; u_lds[prow1] += dv; }
        way_lds[c0] = way0; way_lds[c1] = way1;
        if (l == 0) { u_lds[i] += cum; p_lds[0] = i; }   // col 0: p[0]=i, used at cum=0
        __syncthreads();

        // ---- augment along the path (serial, lane 0) ----
        if (l == 0) {
            int j = jfin;
            for (int s = 0; s <= N && j != 0; ++s) {
                int jn = way_lds[j];
                p_lds[j] = p_lds[jn];
                j = jn;
            }
        }
        __syncthreads();
        prow0 = p_lds[c0];
        prow1 = p_lds[c1];
    }

    // ---- epilogue: out = softmax_row(perm * bias / sqrt(B*n)) ----
    colOf[prow0] = c0;
    colOf[prow1] = c1;
    __syncthreads();

    const float inv_norm = rsqrtf((float)B * (float)N);   // ||perm||_2 = sqrt(B*n) exactly
    float* ob = out + (size_t)b * (N * N);
    #pragma unroll 1
    for (int r = 0; r < N; ++r) {
        int jA = colOf[r + 1];                       // 1-based assigned col of row r
        float s = bias[r * N + (jA - 1)] * inv_norm;
        float e = __expf(s);
        float inv_d = 1.0f / (127.0f + e);           // non-assigned softmax value
        float av = e * inv_d;                        // assigned softmax value
        ob[r * N + l]      = (c0 == jA) ? av : inv_d;
        ob[r * N + l + 64] = (c1 == jA) ? av : inv_d;
    }
}

extern "C" void kernel_launch(void* const* d_in, const int* in_sizes, int n_in,
                              void* d_out, int out_size, void* d_ws, size_t ws_size,
                              hipStream_t stream) {
    const float* x    = (const float*)d_in[0];
    const float* bias = (const float*)d_in[1];
    float* out = (float*)d_out;
    int B = in_sizes[0] / (N * N);
    hipLaunchKernelGGL(lsa_solve_kernel, dim3(B), dim3(64), 0, stream, x, bias, out, B);
}

// Round 2
// 479.359 us; speedup vs baseline: 2.3115x; 2.3115x over previous
//
#include <hip/hip_runtime.h>
#include <hip/hip_fp16.h>

#define N 128
#define INF_ 1e9f

// float -> order-preserving u32 (ascending); NaN sorts above all finite values
__device__ __forceinline__ unsigned f2ord(float f) {
    unsigned b = __float_as_uint(f);
    return b ^ ((unsigned)((int)b >> 31) | 0x80000000u);
}
__device__ __forceinline__ float ord2f(unsigned k) {
    unsigned b = k ^ ((unsigned)((int)(~k) >> 31) | 0x80000000u);
    return __uint_as_float(b);
}

template <int CTRL>
__device__ __forceinline__ int dppmov(int v) {
    return __builtin_amdgcn_update_dpp(v, v, CTRL, 0xF, 0xF, false);
}

// One batch per 64-lane wave. Lane l owns columns c0=l+1, c1=l+65 (1-based).
// Costs in LDS as packed half2 -> 32 KiB -> 4 blocks/CU (LDS-capped).
__global__ void __launch_bounds__(64) lsa_solve_kernel(
        const float* __restrict__ x, const float* __restrict__ bias,
        float* __restrict__ out, int B) {
    __shared__ unsigned Cs[N][64];       // packed fp16 costs (= -x)
    __shared__ float u_lds[N + 1];
    __shared__ int   p_lds[N + 1];       // p[j] = row assigned to col j, 0 = free
    __shared__ int   way_lds[N + 1];
    __shared__ int   colOf[N + 1];       // row -> col
    __shared__ int   rowOwner[N + 1];    // init claim arbitration
    __shared__ int   rowAssigned[N + 1];

    const int b = blockIdx.x;
    const int l = threadIdx.x;
    const int c0 = l + 1, c1 = l + 65;
    const float* xb = x + (size_t)b * (N * N);

    // ---- stage costs into LDS (coalesced, fp16-packed) ----
    #pragma unroll 4
    for (int r = 0; r < N; ++r) {
        float v0 = xb[r * N + l];
        float v1 = xb[r * N + l + 64];
        __half2 h = __floats2half2_rn(-v0, -v1);   // minimize -x
        Cs[r][l] = __builtin_bit_cast(unsigned, h);
    }
    u_lds[l] = 0.f;  u_lds[l + 64] = 0.f;
    p_lds[l] = 0;    p_lds[l + 64] = 0;
    rowOwner[l] = 0x7FFFFFFF;  rowOwner[l + 64] = 0x7FFFFFFF;
    rowAssigned[l] = 0;        rowAssigned[l + 64] = 0;
    if (l == 0) { u_lds[128] = 0.f; p_lds[128] = 0; rowOwner[128] = 0x7FFFFFFF; rowAssigned[128] = 0; }
    __syncthreads();

    // ---- JV-style init: column reduction + greedy claim ----
    float m0 = INF_, m1 = INF_; int am0 = 1, am1 = 1;
    #pragma unroll 1
    for (int r = 0; r < N; ++r) {
        __half2 h = __builtin_bit_cast(__half2, Cs[r][l]);
        float f0 = __low2float(h), f1 = __high2float(h);
        if (f0 < m0) { m0 = f0; am0 = r + 1; }
        if (f1 < m1) { m1 = f1; am1 = r + 1; }
    }
    float v0r = m0, v1r = m1;        // v[j] = column minimum (feasible potentials)
    atomicMin(&rowOwner[am0], c0);
    atomicMin(&rowOwner[am1], c1);
    __syncthreads();
    int prow0 = (rowOwner[am0] == c0) ? am0 : 0;
    int prow1 = (rowOwner[am1] == c1) ? am1 : 0;
    p_lds[c0] = prow0;
    p_lds[c1] = prow1;
    if (prow0) rowAssigned[am0] = 1;
    if (prow1) rowAssigned[am1] = 1;
    float uprow0 = 0.f, uprow1 = 0.f;  // cached u[prow0], u[prow1] (u==0 after init)
    __syncthreads();

    // ---- SAP augmentations for remaining free rows ----
    #pragma unroll 1
    for (int i = 1; i <= N; ++i) {
        if (rowAssigned[i]) continue;                 // uniform branch

        float dist0 = INF_, dist1 = INF_;             // absolute distances (minv + cum)
        int   way0 = 0, way1 = 0;
        float cumAt0 = 0.f, cumAt1 = 0.f;
        float cum = 0.f, base = 0.f;                  // base = cum - u[i0]; u[root]=0
        int   j0 = 0, i0 = i;

        #pragma unroll 1
        for (int it = 0; it <= N; ++it) {
            // mark winner col used: dist=NaN excludes it from all future updates/minima
            if (c0 == j0) { cumAt0 = cum; dist0 = __int_as_float(0x7FC00000); }
            if (c1 == j0) { cumAt1 = cum; dist1 = __int_as_float(0x7FC00000); }

            __half2 h = __builtin_bit_cast(__half2, Cs[i0 - 1][l]);
            float cand0 = __low2float(h)  - v0r + base;   // C - u[i0] - v[j] + cum
            float cand1 = __high2float(h) - v1r + base;
            if (cand0 < dist0) { dist0 = cand0; way0 = j0; }
            if (cand1 < dist1) { dist1 = cand1; way1 = j0; }

            // local min over my 2 columns (tie -> lower col)
            unsigned k0 = f2ord(dist0), k1 = f2ord(dist1);
            unsigned key; int cp; int uub;
            if (k1 < k0) { key = k1; cp = (c1 << 8) | prow1; uub = __float_as_int(uprow1); }
            else         { key = k0; cp = (c0 << 8) | prow0; uub = __float_as_int(uprow0); }

            // 16-lane reduction via DPP row_ror 1,2,4,8 (VALU-speed)
            { unsigned ok=(unsigned)dppmov<0x121>((int)key); int oc=dppmov<0x121>(cp), ou=dppmov<0x121>(uub);
              if (ok < key) { key=ok; cp=oc; uub=ou; } }
            { unsigned ok=(unsigned)dppmov<0x122>((int)key); int oc=dppmov<0x122>(cp), ou=dppmov<0x122>(uub);
              if (ok < key) { key=ok; cp=oc; uub=ou; } }
            { unsigned ok=(unsigned)dppmov<0x124>((int)key); int oc=dppmov<0x124>(cp), ou=dppmov<0x124>(uub);
              if (ok < key) { key=ok; cp=oc; uub=ou; } }
            { unsigned ok=(unsigned)dppmov<0x128>((int)key); int oc=dppmov<0x128>(cp), ou=dppmov<0x128>(uub);
              if (ok < key) { key=ok; cp=oc; uub=ou; } }

            // cross-group finish: 4 group winners -> SGPR scalar tournament
            unsigned gk0 = (unsigned)__builtin_amdgcn_readlane((int)key, 0);
            int      gc0 = __builtin_amdgcn_readlane(cp, 0);
            int      gu0 = __builtin_amdgcn_readlane(uub, 0);
            unsigned gk1 = (unsigned)__builtin_amdgcn_readlane((int)key, 16);
            int      gc1 = __builtin_amdgcn_readlane(cp, 16);
            int      gu1 = __builtin_amdgcn_readlane(uub, 16);
            unsigned gk2 = (unsigned)__builtin_amdgcn_readlane((int)key, 32);
            int      gc2 = __builtin_amdgcn_readlane(cp, 32);
            int      gu2 = __builtin_amdgcn_readlane(uub, 32);
            unsigned gk3 = (unsigned)__builtin_amdgcn_readlane((int)key, 48);
            int      gc3 = __builtin_amdgcn_readlane(cp, 48);
            int      gu3 = __builtin_amdgcn_readlane(uub, 48);
            unsigned kw = gk0; int cw = gc0, uw = gu0;
            if (gk1 < kw || (gk1 == kw && gc1 < cw)) { kw = gk1; cw = gc1; uw = gu1; }
            if (gk2 < kw || (gk2 == kw && gc2 < cw)) { kw = gk2; cw = gc2; uw = gu2; }
            if (gk3 < kw || (gk3 == kw && gc3 < cw)) { kw = gk3; cw = gc3; uw = gu3; }

            cum  = ord2f(kw);
            j0   = cw >> 8;
            i0   = cw & 0xFF;
            base = cum - __int_as_float(uw);
            if (i0 == 0) break;                        // reached a free column
        }

        // ---- deferred potential updates ----
        bool used0 = (__float_as_uint(dist0) == 0x7FC00000u);
        bool used1 = (__float_as_uint(dist1) == 0x7FC00000u);
        if (used0) { float dv = cum - cumAt0; v0r -= dv; u_lds[prow0] += dv; }
        if (used1) { float dv = cum - cumAt1; v1r -= dv; u_lds[prow1] += dv; }
        way_lds[c0] = way0; way_lds[c1] = way1;
        if (l == 0) { u_lds[i] += cum; p_lds[0] = i; }
        __syncthreads();

        // ---- augment along the path (serial, lane 0) ----
        if (l == 0) {
            int j = j0;
            for (int s = 0; s <= N && j != 0; ++s) {
                int jn = way_lds[j];
                p_lds[j] = p_lds[jn];
                j = jn;
            }
        }
        __syncthreads();
        prow0 = p_lds[c0]; uprow0 = u_lds[prow0];
        prow1 = p_lds[c1]; uprow1 = u_lds[prow1];
    }

    // ---- epilogue: out = softmax_row(perm * bias / sqrt(B*n)) ----
    colOf[prow0] = c0;
    colOf[prow1] = c1;
    __syncthreads();

    const float inv_norm = rsqrtf((float)B * (float)N);   // ||perm||_2 = sqrt(B*n)
    float* ob = out + (size_t)b * (N * N);
    #pragma unroll 1
    for (int r = 0; r < N; ++r) {
        int jA = colOf[r + 1];
        float s = bias[r * N + (jA - 1)] * inv_norm;
        float e = __expf(s);
        float inv_d = 1.0f / (127.0f + e);
        float av = e * inv_d;
        ob[r * N + l]      = (c0 == jA) ? av : inv_d;
        ob[r * N + l + 64] = (c1 == jA) ? av : inv_d;
    }
}

extern "C" void kernel_launch(void* const* d_in, const int* in_sizes, int n_in,
                              void* d_out, int out_size, void* d_ws, size_t ws_size,
                              hipStream_t stream) {
    const float* x    = (const float*)d_in[0];
    const float* bias = (const float*)d_in[1];
    float* out = (float*)d_out;
    int B = in_sizes[0] / (N * N);
    hipLaunchKernelGGL(lsa_solve_kernel, dim3(B), dim3(64), 0, stream, x, bias, out, B);
}